// Round 1
// baseline (825.367 us; speedup 1.0000x reference)
//
#include <hip/hip_runtime.h>
#include <math.h>

#define BB 4
#define NN 512
#define DIMX 384
#define HH 8
#define DKK 16
#define DVV 16
#define PKK 4
#define PVV 8
#define PDD 64

static constexpr float EPSV = 1e-8f;
static constexpr float SCALAR_SCALE = 0.14433756729740643f;  // (3*16)^-0.5
static constexpr float POINT_SCALE  = 0.1360827634879543f;   // (3*4*4.5)^-0.5
static constexpr float PAIR_SCALE   = 0.5773502691896258f;   // 3^-0.5

// ---------------- rope table ----------------
__global__ void k_rope(float* __restrict__ cos_t, float* __restrict__ sin_t) {
    int n = blockIdx.x * blockDim.x + threadIdx.x;
    if (n >= NN) return;
#pragma unroll
    for (int i = 0; i < 8; ++i) {
        float invf = powf(10000.0f, -(float)i / 8.0f);
        float f = (float)n * invf;
        cos_t[n * 8 + i] = cosf(f);
        sin_t[n * 8 + i] = sinf(f);
    }
}

// ---------------- projections + transforms ----------------
__global__ __launch_bounds__(256) void k_proj(
    const float* __restrict__ x, const float* __restrict__ rot,
    const float* __restrict__ trans, const int* __restrict__ pos_ids,
    const float* __restrict__ Wq_s, const float* __restrict__ Wk_s, const float* __restrict__ Wv_s,
    const float* __restrict__ Wq_p, const float* __restrict__ Wk_p, const float* __restrict__ Wv_p,
    const float* __restrict__ cos_t, const float* __restrict__ sin_t,
    float* __restrict__ qsg, float* __restrict__ ksg, float* __restrict__ vsg,
    float* __restrict__ qpg, float* __restrict__ kpg, float* __restrict__ vpg,
    float* __restrict__ qqg, float* __restrict__ kkg)
{
    __shared__ float xl[8][DIMX];
    __shared__ float raw[8][768];
    const int t = threadIdx.x;
    const int tok0 = blockIdx.x * 8;

    // load x tile (8 x 384)
    {
        const float4* xg = (const float4*)(x + (size_t)tok0 * DIMX);
        float4* xl4 = (float4*)&xl[0][0];
#pragma unroll
        for (int k = 0; k < 3; ++k) xl4[t + 256 * k] = xg[t + 256 * k];
    }
    __syncthreads();

    const int tok = t >> 5, l = t & 31;
    // GEMM: each thread computes 6 float4 output columns for its token
    {
        float4 acc[6];
        const float* wb[6];
        int st[6];
#pragma unroll
        for (int m = 0; m < 6; ++m) {
            int f = l + 32 * m;     // float4-column index 0..191
            const float* w; int out, c;
            if (f < 32)       { w = Wq_s; out = 128; c = 4 * f; }
            else if (f < 64)  { w = Wk_s; out = 128; c = 4 * f - 128; }
            else if (f < 96)  { w = Wv_s; out = 128; c = 4 * f - 256; }
            else if (f < 120) { w = Wq_p; out = 96;  c = 4 * f - 384; }
            else if (f < 144) { w = Wk_p; out = 96;  c = 4 * f - 480; }
            else              { w = Wv_p; out = 192; c = 4 * f - 576; }
            wb[m] = w + c; st[m] = out;
            acc[m] = make_float4(0.f, 0.f, 0.f, 0.f);
        }
        for (int dd = 0; dd < DIMX; ++dd) {
            float xv = xl[tok][dd];
#pragma unroll
            for (int m = 0; m < 6; ++m) {
                float4 wv = *(const float4*)(wb[m] + (size_t)dd * st[m]);
                acc[m].x = fmaf(xv, wv.x, acc[m].x);
                acc[m].y = fmaf(xv, wv.y, acc[m].y);
                acc[m].z = fmaf(xv, wv.z, acc[m].z);
                acc[m].w = fmaf(xv, wv.w, acc[m].w);
            }
        }
#pragma unroll
        for (int m = 0; m < 6; ++m) {
            int f = l + 32 * m;
            *(float4*)&raw[tok][4 * f] = acc[m];
        }
    }
    __syncthreads();

    // epilogue: per (token, h, q) transforms. l = h*4 + q
    const int h = l >> 2, q = l & 3;
    const int n_g = tok0 + tok;
    const int b = n_g / NN;
    const int pos = pos_ids[n_g];
    const float* Rm = rot + (size_t)n_g * 9;
    const float tr0 = trans[n_g * 3 + 0], tr1 = trans[n_g * 3 + 1], tr2 = trans[n_g * 3 + 2];
    const size_t rowi = ((size_t)(b * HH + h)) * NN + (n_g - b * NN);

    // rope on qs/ks, copy vs: 4 d's per thread
#pragma unroll
    for (int dd0 = 0; dd0 < 4; ++dd0) {
        int dd = q * 4 + dd0;
        int i8 = dd & 7;
        float c = cos_t[pos * 8 + i8], s = sin_t[pos * 8 + i8];
        float xq = raw[tok][h * 16 + dd];
        float rq = (dd < 8) ? -raw[tok][h * 16 + dd + 8] : raw[tok][h * 16 + dd - 8];
        qsg[rowi * DKK + dd] = fmaf(xq, c, rq * s);
        float xk = raw[tok][128 + h * 16 + dd];
        float rk = (dd < 8) ? -raw[tok][128 + h * 16 + dd + 8] : raw[tok][128 + h * 16 + dd - 8];
        ksg[rowi * DKK + dd] = fmaf(xk, c, rk * s);
        vsg[rowi * DVV + dd] = raw[tok][256 + h * 16 + dd];
    }

    // q/k points: point p = q
    float qqp = 0.f, kkp = 0.f;
    {
        const int p = q;
        float pc[3], kc[3];
#pragma unroll
        for (int c = 0; c < 3; ++c) {
            pc[c] = raw[tok][384 + h * 12 + p * 3 + c];
            kc[c] = raw[tok][480 + h * 12 + p * 3 + c];
        }
        const float trv[3] = {tr0, tr1, tr2};
#pragma unroll
        for (int r = 0; r < 3; ++r) {
            float vq = trv[r], vk = trv[r];
#pragma unroll
            for (int c = 0; c < 3; ++c) {
                vq = fmaf(pc[c], Rm[c * 3 + r], vq);
                vk = fmaf(kc[c], Rm[c * 3 + r], vk);
            }
            qpg[rowi * 12 + p * 3 + r] = vq;
            kpg[rowi * 12 + p * 3 + r] = vk;
            qqp = fmaf(vq, vq, qqp);
            kkp = fmaf(vk, vk, kkp);
        }
    }
    qqp += __shfl_xor(qqp, 1); qqp += __shfl_xor(qqp, 2);
    kkp += __shfl_xor(kkp, 1); kkp += __shfl_xor(kkp, 2);
    if (q == 0) { qqg[rowi] = qqp; kkg[rowi] = kkp; }

    // v points: p = q and q+4
    {
        const float trv[3] = {tr0, tr1, tr2};
#pragma unroll
        for (int pp = 0; pp < 2; ++pp) {
            int p = q + 4 * pp;
            float pc[3];
#pragma unroll
            for (int c = 0; c < 3; ++c) pc[c] = raw[tok][576 + h * 24 + p * 3 + c];
#pragma unroll
            for (int r = 0; r < 3; ++r) {
                float v = trv[r];
#pragma unroll
                for (int c = 0; c < 3; ++c) v = fmaf(pc[c], Rm[c * 3 + r], v);
                vpg[rowi * 24 + p * 3 + r] = v;
            }
        }
    }
}

// ---------------- helpers ----------------
static __device__ __forceinline__ float dot16(const float* __restrict__ a, const float* __restrict__ g) {
    const float4* g4 = (const float4*)g;
    float4 v0 = g4[0], v1 = g4[1], v2 = g4[2], v3 = g4[3];
    float d = 0.f;
    d = fmaf(a[0],  v0.x, d); d = fmaf(a[1],  v0.y, d); d = fmaf(a[2],  v0.z, d); d = fmaf(a[3],  v0.w, d);
    d = fmaf(a[4],  v1.x, d); d = fmaf(a[5],  v1.y, d); d = fmaf(a[6],  v1.z, d); d = fmaf(a[7],  v1.w, d);
    d = fmaf(a[8],  v2.x, d); d = fmaf(a[9],  v2.y, d); d = fmaf(a[10], v2.z, d); d = fmaf(a[11], v2.w, d);
    d = fmaf(a[12], v3.x, d); d = fmaf(a[13], v3.y, d); d = fmaf(a[14], v3.z, d); d = fmaf(a[15], v3.w, d);
    return d;
}
static __device__ __forceinline__ float dot12(const float* __restrict__ a, const float* __restrict__ g) {
    const float4* g4 = (const float4*)g;
    float4 v0 = g4[0], v1 = g4[1], v2 = g4[2];
    float d = 0.f;
    d = fmaf(a[0], v0.x, d); d = fmaf(a[1],  v0.y, d); d = fmaf(a[2],  v0.z, d); d = fmaf(a[3],  v0.w, d);
    d = fmaf(a[4], v1.x, d); d = fmaf(a[5],  v1.y, d); d = fmaf(a[6],  v1.z, d); d = fmaf(a[7],  v1.w, d);
    d = fmaf(a[8], v2.x, d); d = fmaf(a[9],  v2.y, d); d = fmaf(a[10], v2.z, d); d = fmaf(a[11], v2.w, d);
    return d;
}

// ---------------- fused attention (one block per (b,i)) ----------------
__global__ __launch_bounds__(256) void k_attn(
    const float* __restrict__ pairw,
    const float* __restrict__ rot, const float* __restrict__ trans,
    const float* __restrict__ Wpair, const float* __restrict__ bpair,
    const float* __restrict__ pweights,
    const float* __restrict__ qsg, const float* __restrict__ ksg, const float* __restrict__ vsg,
    const float* __restrict__ qpg, const float* __restrict__ kpg, const float* __restrict__ vpg,
    const float* __restrict__ qqg, const float* __restrict__ kkg,
    float* __restrict__ feats)
{
    __shared__ float pw[128][65];     // pairwise tile, padded
    __shared__ float plds[8][128];    // probs per head
    __shared__ float biasl[8][128];   // pair bias per head (reused for pts in epilogue)
    __shared__ float Wp_l[512];

    const int t = threadIdx.x;
    const int bi = blockIdx.x;         // b*N + i
    const int b = bi >> 9;
    const int h = t >> 5, l = t & 31;

    for (int k = t; k < 512; k += 256) Wp_l[k] = Wpair[k];

    const size_t bhN = ((size_t)(b * HH + h)) * NN;
    const size_t rowq = bhN + (bi & 511);

    float qs_r[16];
    {
        const float4* q4 = (const float4*)(qsg + rowq * 16);
#pragma unroll
        for (int k = 0; k < 4; ++k) {
            float4 v = q4[k];
            qs_r[4*k] = v.x; qs_r[4*k+1] = v.y; qs_r[4*k+2] = v.z; qs_r[4*k+3] = v.w;
        }
    }
    float qp_r[12];
    {
        const float4* q4 = (const float4*)(qpg + rowq * 12);
#pragma unroll
        for (int k = 0; k < 3; ++k) {
            float4 v = q4[k];
            qp_r[4*k] = v.x; qp_r[4*k+1] = v.y; qp_r[4*k+2] = v.z; qp_r[4*k+3] = v.w;
        }
    }
    const float qq_r = qqg[rowq];
    const float pw_h = log1pf(__expf(pweights[h]));
    const float coefP = -0.5f * pw_h * POINT_SCALE;
    const float bp_h = bpair[h];

    float m = -3.0e38f, lsum = 0.f;
    float ap0 = 0.f, ap1 = 0.f, asc = 0.f, apt = 0.f;

    const float* pwrow = pairw + (size_t)bi * NN * PDD;

    for (int jc = 0; jc < NN; jc += 128) {
        __syncthreads();   // protect pw/biasl/plds re-staging
        // stage pairwise tile (128 x 64)
        {
            const float4* src = (const float4*)(pwrow + (size_t)jc * PDD);
#pragma unroll
            for (int k = 0; k < 8; ++k) {
                int f = t + 256 * k;
                int j = f >> 4, d4 = (f & 15) * 4;
                float4 v = src[f];
                pw[j][d4] = v.x; pw[j][d4+1] = v.y; pw[j][d4+2] = v.z; pw[j][d4+3] = v.w;
            }
        }
        __syncthreads();
        // pair bias for this tile: 2 threads per j (d halves)
        {
            const int jl = t >> 1, d0 = (t & 1) * 32;
            float bacc[8];
#pragma unroll
            for (int hh = 0; hh < 8; ++hh) bacc[hh] = 0.f;
            for (int dd = 0; dd < 32; ++dd) {
                float v = pw[jl][d0 + dd];
#pragma unroll
                for (int hh = 0; hh < 8; ++hh) bacc[hh] = fmaf(v, Wp_l[(d0 + dd) * 8 + hh], bacc[hh]);
            }
#pragma unroll
            for (int hh = 0; hh < 8; ++hh) bacc[hh] += __shfl_xor(bacc[hh], 1);
            if ((t & 1) == 0) {
#pragma unroll
                for (int hh = 0; hh < 8; ++hh)
                    biasl[hh][jl] = (bacc[hh] + bpair[hh]) * PAIR_SCALE;
            }
        }
        __syncthreads();
        // logits: thread (h,l) handles j = jc + l + 32s
        float pj[4];
        float cmax = -3.0e38f;
#pragma unroll
        for (int s = 0; s < 4; ++s) {
            const int jl = l + 32 * s;
            const size_t jrow = bhN + (jc + jl);
            float dot  = dot16(qs_r, ksg + jrow * 16);
            float pdot = dot12(qp_r, kpg + jrow * 12);
            float dist = qq_r + kkg[jrow] - 2.f * pdot;
            float lg = fmaf(dot, SCALAR_SCALE, fmaf(coefP, dist, biasl[h][jl]));
            pj[s] = lg;
            cmax = fmaxf(cmax, lg);
        }
#pragma unroll
        for (int off = 16; off > 0; off >>= 1) cmax = fmaxf(cmax, __shfl_xor(cmax, off));
        const float mnew = fmaxf(m, cmax);
        const float scale = __expf(m - mnew);
        float psum = 0.f;
#pragma unroll
        for (int s = 0; s < 4; ++s) { pj[s] = __expf(pj[s] - mnew); psum += pj[s]; }
#pragma unroll
        for (int off = 16; off > 0; off >>= 1) psum += __shfl_xor(psum, off);
        m = mnew;
        lsum = fmaf(lsum, scale, psum);
#pragma unroll
        for (int s = 0; s < 4; ++s) plds[h][l + 32 * s] = pj[s];
        ap0 *= scale; ap1 *= scale; asc *= scale; apt *= scale;
        __syncthreads();
        // accumulate outputs (thread owns fixed output dims)
        const float* vsp = vsg + (bhN + jc) * 16 + l;
        const float* vpp = vpg + (bhN + jc) * 24 + l;
        for (int jl = 0; jl < 128; ++jl) {
            float p = plds[h][jl];
            ap0 = fmaf(p, pw[jl][l], ap0);
            ap1 = fmaf(p, pw[jl][l + 32], ap1);
            if (l < 16) asc = fmaf(p, vsp[jl * 16], asc);
            if (l < 24) apt = fmaf(p, vpp[jl * 24], apt);
        }
    }

    // epilogue
    const float inv_l = 1.f / lsum;
    float* fb = feats + (size_t)bi * 896;
    if (l < 16) fb[h * 16 + l] = asc * inv_l;                 // m_scalar
    fb[384 + h * 64 + l]      = ap0 * inv_l;                  // m_pair
    fb[384 + h * 64 + l + 32] = ap1 * inv_l;
    __syncthreads();
    if (l < 24) biasl[h][l] = apt * inv_l - trans[bi * 3 + (l % 3)];
    __syncthreads();
    if (l < 24) {
        const int p = l / 3, r = l - p * 3;
        const float* Rm = rot + (size_t)bi * 9 + r * 3;   // R[r][c]
        float v = 0.f;
#pragma unroll
        for (int c = 0; c < 3; ++c) v = fmaf(biasl[h][p * 3 + c], Rm[c], v);
        fb[128 + h * 24 + p * 3 + r] = v;                     // m_pts
    }
    if (l < 8) {
        float s2 = EPSV;
#pragma unroll
        for (int c = 0; c < 3; ++c) { float v = biasl[h][l * 3 + c]; s2 = fmaf(v, v, s2); }
        fb[320 + h * 8 + l] = sqrtf(s2);                      // m_norm (rotation-invariant)
    }
    (void)bp_h;
}

// ---------------- output projection ----------------
__global__ __launch_bounds__(256) void k_out(
    const float* __restrict__ feats, const float* __restrict__ Wout,
    const float* __restrict__ bout, float* __restrict__ out)
{
    __shared__ float fl[8][896];
    const int t = threadIdx.x;
    const int tok0 = blockIdx.x * 8;
    {
        const float4* src = (const float4*)(feats + (size_t)tok0 * 896);
        float4* dst = (float4*)&fl[0][0];
#pragma unroll
        for (int k = 0; k < 7; ++k) dst[t + 256 * k] = src[t + 256 * k];
    }
    __syncthreads();
    const int tok = t >> 5, l = t & 31;
    float4 acc[3];
#pragma unroll
    for (int m = 0; m < 3; ++m) acc[m] = make_float4(0.f, 0.f, 0.f, 0.f);
    for (int dd = 0; dd < 896; ++dd) {
        float fv = fl[tok][dd];
        const float* wr = Wout + (size_t)dd * 384;
#pragma unroll
        for (int m = 0; m < 3; ++m) {
            float4 wv = *(const float4*)(wr + 4 * (l + 32 * m));
            acc[m].x = fmaf(fv, wv.x, acc[m].x);
            acc[m].y = fmaf(fv, wv.y, acc[m].y);
            acc[m].z = fmaf(fv, wv.z, acc[m].z);
            acc[m].w = fmaf(fv, wv.w, acc[m].w);
        }
    }
    float* ob = out + (size_t)(tok0 + tok) * 384;
#pragma unroll
    for (int m = 0; m < 3; ++m) {
        int c = 4 * (l + 32 * m);
        float4 bv = *(const float4*)(bout + c);
        float4 r = make_float4(acc[m].x + bv.x, acc[m].y + bv.y, acc[m].z + bv.z, acc[m].w + bv.w);
        *(float4*)(ob + c) = r;
    }
}

extern "C" void kernel_launch(void* const* d_in, const int* in_sizes, int n_in,
                              void* d_out, int out_size, void* d_ws, size_t ws_size,
                              hipStream_t stream) {
    const float* x        = (const float*)d_in[0];
    const float* pairw    = (const float*)d_in[1];
    const float* rot      = (const float*)d_in[2];
    const float* trans    = (const float*)d_in[3];
    const int*   pos      = (const int*)d_in[4];
    // d_in[5] = mask (all true in this problem) — unused
    const float* Wq_s     = (const float*)d_in[6];
    const float* Wk_s     = (const float*)d_in[7];
    const float* Wv_s     = (const float*)d_in[8];
    const float* Wq_p     = (const float*)d_in[9];
    const float* Wk_p     = (const float*)d_in[10];
    const float* Wv_p     = (const float*)d_in[11];
    const float* pweights = (const float*)d_in[12];
    const float* Wpair    = (const float*)d_in[13];
    const float* bpair    = (const float*)d_in[14];
    const float* Wout     = (const float*)d_in[15];
    const float* bout     = (const float*)d_in[16];
    float* out = (float*)d_out;

    float* ws = (float*)d_ws;
    float* cos_t = ws;  ws += 4096;
    float* sin_t = ws;  ws += 4096;
    float* qsg = ws;    ws += BB * HH * NN * DKK;   // 262144
    float* ksg = ws;    ws += BB * HH * NN * DKK;
    float* vsg = ws;    ws += BB * HH * NN * DVV;
    float* qpg = ws;    ws += BB * HH * NN * 12;
    float* kpg = ws;    ws += BB * HH * NN * 12;
    float* vpg = ws;    ws += BB * HH * NN * 24;
    float* qqg = ws;    ws += BB * HH * NN;
    float* kkg = ws;    ws += BB * HH * NN;
    float* feats = ws;  ws += BB * NN * 896;

    k_rope<<<2, 256, 0, stream>>>(cos_t, sin_t);
    k_proj<<<(BB * NN) / 8, 256, 0, stream>>>(x, rot, trans, pos,
        Wq_s, Wk_s, Wv_s, Wq_p, Wk_p, Wv_p, cos_t, sin_t,
        qsg, ksg, vsg, qpg, kpg, vpg, qqg, kkg);
    k_attn<<<BB * NN, 256, 0, stream>>>(pairw, rot, trans, Wpair, bpair, pweights,
        qsg, ksg, vsg, qpg, kpg, vpg, qqg, kkg, feats);
    k_out<<<(BB * NN) / 8, 256, 0, stream>>>(feats, Wout, bout, out);

    (void)in_sizes; (void)n_in; (void)out_size; (void)ws_size;
}

// Round 2
// 484.131 us; speedup vs baseline: 1.7048x; 1.7048x over previous
//
#include <hip/hip_runtime.h>
#include <math.h>

#define BB 4
#define NN 512
#define DIMX 384
#define HH 8
#define DKK 16
#define DVV 16
#define PKK 4
#define PVV 8
#define PDD 64
#define JC 64

static constexpr float EPSV = 1e-8f;
static constexpr float SCALAR_SCALE = 0.14433756729740643f;  // (3*16)^-0.5
static constexpr float POINT_SCALE  = 0.1360827634879543f;   // (3*4*4.5)^-0.5
static constexpr float PAIR_SCALE   = 0.5773502691896258f;   // 3^-0.5

// ---------------- rope table ----------------
__global__ void k_rope(float* __restrict__ cos_t, float* __restrict__ sin_t) {
    int n = blockIdx.x * blockDim.x + threadIdx.x;
    if (n >= NN) return;
#pragma unroll
    for (int i = 0; i < 8; ++i) {
        float invf = powf(10000.0f, -(float)i / 8.0f);
        float f = (float)n * invf;
        cos_t[n * 8 + i] = cosf(f);
        sin_t[n * 8 + i] = sinf(f);
    }
}

// ---------------- projections + transforms ----------------
__global__ __launch_bounds__(256) void k_proj(
    const float* __restrict__ x, const float* __restrict__ rot,
    const float* __restrict__ trans, const int* __restrict__ pos_ids,
    const float* __restrict__ Wq_s, const float* __restrict__ Wk_s, const float* __restrict__ Wv_s,
    const float* __restrict__ Wq_p, const float* __restrict__ Wk_p, const float* __restrict__ Wv_p,
    const float* __restrict__ cos_t, const float* __restrict__ sin_t,
    float* __restrict__ qsg, float* __restrict__ ksg, float* __restrict__ vsg,
    float* __restrict__ qpg, float* __restrict__ kpg, float* __restrict__ vpg,
    float* __restrict__ qqg, float* __restrict__ kkg)
{
    __shared__ float xl[8][DIMX];
    __shared__ float raw[8][768];
    const int t = threadIdx.x;
    const int tok0 = blockIdx.x * 8;

    {
        const float4* xg = (const float4*)(x + (size_t)tok0 * DIMX);
        float4* xl4 = (float4*)&xl[0][0];
#pragma unroll
        for (int k = 0; k < 3; ++k) xl4[t + 256 * k] = xg[t + 256 * k];
    }
    __syncthreads();

    const int tok = t >> 5, l = t & 31;
    {
        float4 acc[6];
        const float* wb[6];
        int st[6];
#pragma unroll
        for (int m = 0; m < 6; ++m) {
            int f = l + 32 * m;
            const float* w; int out, c;
            if (f < 32)       { w = Wq_s; out = 128; c = 4 * f; }
            else if (f < 64)  { w = Wk_s; out = 128; c = 4 * f - 128; }
            else if (f < 96)  { w = Wv_s; out = 128; c = 4 * f - 256; }
            else if (f < 120) { w = Wq_p; out = 96;  c = 4 * f - 384; }
            else if (f < 144) { w = Wk_p; out = 96;  c = 4 * f - 480; }
            else              { w = Wv_p; out = 192; c = 4 * f - 576; }
            wb[m] = w + c; st[m] = out;
            acc[m] = make_float4(0.f, 0.f, 0.f, 0.f);
        }
        for (int dd = 0; dd < DIMX; ++dd) {
            float xv = xl[tok][dd];
#pragma unroll
            for (int m = 0; m < 6; ++m) {
                float4 wv = *(const float4*)(wb[m] + (size_t)dd * st[m]);
                acc[m].x = fmaf(xv, wv.x, acc[m].x);
                acc[m].y = fmaf(xv, wv.y, acc[m].y);
                acc[m].z = fmaf(xv, wv.z, acc[m].z);
                acc[m].w = fmaf(xv, wv.w, acc[m].w);
            }
        }
#pragma unroll
        for (int m = 0; m < 6; ++m) {
            int f = l + 32 * m;
            *(float4*)&raw[tok][4 * f] = acc[m];
        }
    }
    __syncthreads();

    const int h = l >> 2, q = l & 3;
    const int n_g = tok0 + tok;
    const int b = n_g / NN;
    const int pos = pos_ids[n_g];
    const float* Rm = rot + (size_t)n_g * 9;
    const float tr0 = trans[n_g * 3 + 0], tr1 = trans[n_g * 3 + 1], tr2 = trans[n_g * 3 + 2];
    const size_t rowi = ((size_t)(b * HH + h)) * NN + (n_g - b * NN);

#pragma unroll
    for (int dd0 = 0; dd0 < 4; ++dd0) {
        int dd = q * 4 + dd0;
        int i8 = dd & 7;
        float c = cos_t[pos * 8 + i8], s = sin_t[pos * 8 + i8];
        float xq = raw[tok][h * 16 + dd];
        float rq = (dd < 8) ? -raw[tok][h * 16 + dd + 8] : raw[tok][h * 16 + dd - 8];
        qsg[rowi * DKK + dd] = fmaf(xq, c, rq * s);
        float xk = raw[tok][128 + h * 16 + dd];
        float rk = (dd < 8) ? -raw[tok][128 + h * 16 + dd + 8] : raw[tok][128 + h * 16 + dd - 8];
        ksg[rowi * DKK + dd] = fmaf(xk, c, rk * s);
        vsg[rowi * DVV + dd] = raw[tok][256 + h * 16 + dd];
    }

    float qqp = 0.f, kkp = 0.f;
    {
        const int p = q;
        float pc[3], kc[3];
#pragma unroll
        for (int c = 0; c < 3; ++c) {
            pc[c] = raw[tok][384 + h * 12 + p * 3 + c];
            kc[c] = raw[tok][480 + h * 12 + p * 3 + c];
        }
        const float trv[3] = {tr0, tr1, tr2};
#pragma unroll
        for (int r = 0; r < 3; ++r) {
            float vq = trv[r], vk = trv[r];
#pragma unroll
            for (int c = 0; c < 3; ++c) {
                vq = fmaf(pc[c], Rm[c * 3 + r], vq);
                vk = fmaf(kc[c], Rm[c * 3 + r], vk);
            }
            qpg[rowi * 12 + p * 3 + r] = vq;
            kpg[rowi * 12 + p * 3 + r] = vk;
            qqp = fmaf(vq, vq, qqp);
            kkp = fmaf(vk, vk, kkp);
        }
    }
    qqp += __shfl_xor(qqp, 1); qqp += __shfl_xor(qqp, 2);
    kkp += __shfl_xor(kkp, 1); kkp += __shfl_xor(kkp, 2);
    if (q == 0) { qqg[rowi] = qqp; kkg[rowi] = kkp; }

    {
        const float trv[3] = {tr0, tr1, tr2};
#pragma unroll
        for (int pp = 0; pp < 2; ++pp) {
            int p = q + 4 * pp;
            float pc[3];
#pragma unroll
            for (int c = 0; c < 3; ++c) pc[c] = raw[tok][576 + h * 24 + p * 3 + c];
#pragma unroll
            for (int r = 0; r < 3; ++r) {
                float v = trv[r];
#pragma unroll
                for (int c = 0; c < 3; ++c) v = fmaf(pc[c], Rm[c * 3 + r], v);
                vpg[rowi * 24 + p * 3 + r] = v;
            }
        }
    }
}

// ---------------- fused attention (one block per (b,i)) ----------------
__global__ __launch_bounds__(256, 4) void k_attn(
    const float* __restrict__ pairw,
    const float* __restrict__ rot, const float* __restrict__ trans,
    const float* __restrict__ Wpair, const float* __restrict__ bpair,
    const float* __restrict__ pweights,
    const float* __restrict__ qsg, const float* __restrict__ ksg, const float* __restrict__ vsg,
    const float* __restrict__ qpg, const float* __restrict__ kpg, const float* __restrict__ vpg,
    const float* __restrict__ qqg, const float* __restrict__ kkg,
    float* __restrict__ feats)
{
    __shared__ float pw[JC][65];       // pairwise tile, +1 pad: conflict-free row-per-lane b32
    __shared__ float plds[HH][JC];     // probs (same-wave write->read, no barrier needed)
    __shared__ float biasl[HH][JC];    // pair bias
    __shared__ float Wp_t[8 * 64];     // transposed [h][d]
    __shared__ float qsh[HH][16];
    __shared__ float qph[HH][12];
    __shared__ float qqh[HH];
    __shared__ float bph[HH];

    const int t = threadIdx.x;
    const int bi = blockIdx.x;
    const int b = bi >> 9;
    const int h = t >> 5, l = t & 31;

    // init: transpose W_pair into [h][64], stage q for all heads
    {
        int d = t >> 3, hh = t & 7;
        Wp_t[hh * 64 + d] = Wpair[t];
        int t2 = t + 256; d = t2 >> 3; hh = t2 & 7;
        Wp_t[hh * 64 + d] = Wpair[t2];
    }
    const size_t bhN = ((size_t)(b * HH + h)) * NN;
    const size_t rowq = bhN + (bi & 511);
    if (l < 16) qsh[h][l] = qsg[rowq * 16 + l];
    if (l < 12) qph[h][l] = qpg[rowq * 12 + l];
    if (l == 0) qqh[h] = qqg[rowq];
    if (t < 8)  bph[t] = bpair[t];
    const float coefP = -0.5f * log1pf(__expf(pweights[h])) * POINT_SCALE;

    float m = -3.0e38f, lsum = 0.f;
    float ascd[16], aptd[24];
#pragma unroll
    for (int d = 0; d < 16; ++d) ascd[d] = 0.f;
#pragma unroll
    for (int d = 0; d < 24; ++d) aptd[d] = 0.f;
    float ap0 = 0.f, ap1 = 0.f;

    const float* pwrow = pairw + (size_t)bi * NN * PDD;

    for (int jc = 0; jc < NN; jc += JC) {
        __syncthreads();   // prev pair-acc done with pw; qsh/Wp_t ready on first iter
        // stage pairwise tile (64 x 64)
        {
            const float4* src = (const float4*)(pwrow + (size_t)jc * PDD);
#pragma unroll
            for (int k = 0; k < 4; ++k) {
                int f = t + 256 * k;
                int j = f >> 4, d4 = (f & 15) * 4;
                float4 v = src[f];
                pw[j][d4] = v.x; pw[j][d4 + 1] = v.y; pw[j][d4 + 2] = v.z; pw[j][d4 + 3] = v.w;
            }
        }
        __syncthreads();
        // pair bias: 4 threads per j, 16 d each
        {
            const int jl = t >> 2, d0 = (t & 3) * 16;
            float bacc[8];
#pragma unroll
            for (int hh = 0; hh < 8; ++hh) bacc[hh] = 0.f;
#pragma unroll
            for (int dd = 0; dd < 16; ++dd) {
                float v = pw[jl][d0 + dd];
#pragma unroll
                for (int hh = 0; hh < 8; ++hh) bacc[hh] = fmaf(v, Wp_t[hh * 64 + d0 + dd], bacc[hh]);
            }
#pragma unroll
            for (int hh = 0; hh < 8; ++hh) {
                bacc[hh] += __shfl_xor(bacc[hh], 1);
                bacc[hh] += __shfl_xor(bacc[hh], 2);
            }
            if ((t & 3) == 0) {
#pragma unroll
                for (int hh = 0; hh < 8; ++hh)
                    biasl[hh][jl] = (bacc[hh] + bph[hh]) * PAIR_SCALE;
            }
        }
        __syncthreads();
        // logits: lane (h,l) handles j = jc + l + 32s
        float pj[2];
        float cmax = -3.0e38f;
        {
            const float4 qs0 = *(const float4*)&qsh[h][0];
            const float4 qs1 = *(const float4*)&qsh[h][4];
            const float4 qs2 = *(const float4*)&qsh[h][8];
            const float4 qs3 = *(const float4*)&qsh[h][12];
            const float4 qp0 = *(const float4*)&qph[h][0];
            const float4 qp1 = *(const float4*)&qph[h][4];
            const float4 qp2 = *(const float4*)&qph[h][8];
            const float qq_r = qqh[h];
#pragma unroll
            for (int s = 0; s < 2; ++s) {
                const int jl = l + 32 * s;
                const size_t jrow = bhN + jc + jl;
                const float4* kr = (const float4*)(ksg + jrow * 16);
                float4 k0 = kr[0], k1 = kr[1], k2 = kr[2], k3 = kr[3];
                float dot = 0.f;
                dot = fmaf(qs0.x, k0.x, dot); dot = fmaf(qs0.y, k0.y, dot);
                dot = fmaf(qs0.z, k0.z, dot); dot = fmaf(qs0.w, k0.w, dot);
                dot = fmaf(qs1.x, k1.x, dot); dot = fmaf(qs1.y, k1.y, dot);
                dot = fmaf(qs1.z, k1.z, dot); dot = fmaf(qs1.w, k1.w, dot);
                dot = fmaf(qs2.x, k2.x, dot); dot = fmaf(qs2.y, k2.y, dot);
                dot = fmaf(qs2.z, k2.z, dot); dot = fmaf(qs2.w, k2.w, dot);
                dot = fmaf(qs3.x, k3.x, dot); dot = fmaf(qs3.y, k3.y, dot);
                dot = fmaf(qs3.z, k3.z, dot); dot = fmaf(qs3.w, k3.w, dot);
                const float4* kp = (const float4*)(kpg + jrow * 12);
                float4 p0 = kp[0], p1 = kp[1], p2 = kp[2];
                float pdot = 0.f;
                pdot = fmaf(qp0.x, p0.x, pdot); pdot = fmaf(qp0.y, p0.y, pdot);
                pdot = fmaf(qp0.z, p0.z, pdot); pdot = fmaf(qp0.w, p0.w, pdot);
                pdot = fmaf(qp1.x, p1.x, pdot); pdot = fmaf(qp1.y, p1.y, pdot);
                pdot = fmaf(qp1.z, p1.z, pdot); pdot = fmaf(qp1.w, p1.w, pdot);
                pdot = fmaf(qp2.x, p2.x, pdot); pdot = fmaf(qp2.y, p2.y, pdot);
                pdot = fmaf(qp2.z, p2.z, pdot); pdot = fmaf(qp2.w, p2.w, pdot);
                float dist = qq_r + kkg[jrow] - 2.f * pdot;
                float lg = fmaf(dot, SCALAR_SCALE, fmaf(coefP, dist, biasl[h][jl]));
                pj[s] = lg;
                cmax = fmaxf(cmax, lg);
            }
        }
#pragma unroll
        for (int off = 16; off > 0; off >>= 1) cmax = fmaxf(cmax, __shfl_xor(cmax, off));
        const float mnew = fmaxf(m, cmax);
        const float scale = __expf(m - mnew);
        pj[0] = __expf(pj[0] - mnew);
        pj[1] = __expf(pj[1] - mnew);
        float psum = pj[0] + pj[1];
#pragma unroll
        for (int off = 16; off > 0; off >>= 1) psum += __shfl_xor(psum, off);
        m = mnew;
        lsum = fmaf(lsum, scale, psum);
        plds[h][l] = pj[0];
        plds[h][l + 32] = pj[1];
        // rescale accumulators
#pragma unroll
        for (int d = 0; d < 16; ++d) ascd[d] *= scale;
#pragma unroll
        for (int d = 0; d < 24; ++d) aptd[d] *= scale;
        ap0 *= scale; ap1 *= scale;
        // j-parallel v accumulation (lane owns j = jc+l+32s, coalesced row loads)
#pragma unroll
        for (int s = 0; s < 2; ++s) {
            const size_t jrow = bhN + jc + l + 32 * s;
            const float p = pj[s];
            const float4* vr = (const float4*)(vsg + jrow * 16);
            float4 a0 = vr[0], a1 = vr[1], a2 = vr[2], a3 = vr[3];
            ascd[0]  = fmaf(p, a0.x, ascd[0]);  ascd[1]  = fmaf(p, a0.y, ascd[1]);
            ascd[2]  = fmaf(p, a0.z, ascd[2]);  ascd[3]  = fmaf(p, a0.w, ascd[3]);
            ascd[4]  = fmaf(p, a1.x, ascd[4]);  ascd[5]  = fmaf(p, a1.y, ascd[5]);
            ascd[6]  = fmaf(p, a1.z, ascd[6]);  ascd[7]  = fmaf(p, a1.w, ascd[7]);
            ascd[8]  = fmaf(p, a2.x, ascd[8]);  ascd[9]  = fmaf(p, a2.y, ascd[9]);
            ascd[10] = fmaf(p, a2.z, ascd[10]); ascd[11] = fmaf(p, a2.w, ascd[11]);
            ascd[12] = fmaf(p, a3.x, ascd[12]); ascd[13] = fmaf(p, a3.y, ascd[13]);
            ascd[14] = fmaf(p, a3.z, ascd[14]); ascd[15] = fmaf(p, a3.w, ascd[15]);
            const float4* vp = (const float4*)(vpg + jrow * 24);
            float4 b0 = vp[0], b1 = vp[1], b2 = vp[2], b3 = vp[3], b4 = vp[4], b5 = vp[5];
            aptd[0]  = fmaf(p, b0.x, aptd[0]);  aptd[1]  = fmaf(p, b0.y, aptd[1]);
            aptd[2]  = fmaf(p, b0.z, aptd[2]);  aptd[3]  = fmaf(p, b0.w, aptd[3]);
            aptd[4]  = fmaf(p, b1.x, aptd[4]);  aptd[5]  = fmaf(p, b1.y, aptd[5]);
            aptd[6]  = fmaf(p, b1.z, aptd[6]);  aptd[7]  = fmaf(p, b1.w, aptd[7]);
            aptd[8]  = fmaf(p, b2.x, aptd[8]);  aptd[9]  = fmaf(p, b2.y, aptd[9]);
            aptd[10] = fmaf(p, b2.z, aptd[10]); aptd[11] = fmaf(p, b2.w, aptd[11]);
            aptd[12] = fmaf(p, b3.x, aptd[12]); aptd[13] = fmaf(p, b3.y, aptd[13]);
            aptd[14] = fmaf(p, b3.z, aptd[14]); aptd[15] = fmaf(p, b3.w, aptd[15]);
            aptd[16] = fmaf(p, b4.x, aptd[16]); aptd[17] = fmaf(p, b4.y, aptd[17]);
            aptd[18] = fmaf(p, b4.z, aptd[18]); aptd[19] = fmaf(p, b4.w, aptd[19]);
            aptd[20] = fmaf(p, b5.x, aptd[20]); aptd[21] = fmaf(p, b5.y, aptd[21]);
            aptd[22] = fmaf(p, b5.z, aptd[22]); aptd[23] = fmaf(p, b5.w, aptd[23]);
        }
        // res_pair: output-stationary, 4-j vectorized via float4 prob reads (same wave)
#pragma unroll
        for (int u = 0; u < JC / 4; ++u) {
            float4 p4 = *(const float4*)&plds[h][4 * u];
            ap0 = fmaf(p4.x, pw[4 * u + 0][l], ap0); ap1 = fmaf(p4.x, pw[4 * u + 0][l + 32], ap1);
            ap0 = fmaf(p4.y, pw[4 * u + 1][l], ap0); ap1 = fmaf(p4.y, pw[4 * u + 1][l + 32], ap1);
            ap0 = fmaf(p4.z, pw[4 * u + 2][l], ap0); ap1 = fmaf(p4.z, pw[4 * u + 2][l + 32], ap1);
            ap0 = fmaf(p4.w, pw[4 * u + 3][l], ap0); ap1 = fmaf(p4.w, pw[4 * u + 3][l + 32], ap1);
        }
    }

    // epilogue: butterfly-reduce per-lane partials across the 32-lane half-wave
#pragma unroll
    for (int off = 16; off > 0; off >>= 1) {
#pragma unroll
        for (int d = 0; d < 16; ++d) ascd[d] += __shfl_xor(ascd[d], off);
#pragma unroll
        for (int d = 0; d < 24; ++d) aptd[d] += __shfl_xor(aptd[d], off);
    }
    const float inv_l = 1.f / lsum;
    float* fb = feats + (size_t)bi * 896;
    if (l < 16) fb[h * 16 + l] = ascd[l] * inv_l;             // m_scalar
    fb[384 + h * 64 + l]      = ap0 * inv_l;                  // m_pair
    fb[384 + h * 64 + l + 32] = ap1 * inv_l;
    const float tr0 = trans[bi * 3 + 0], tr1 = trans[bi * 3 + 1], tr2 = trans[bi * 3 + 2];
    if (l < 24) {
        const int p = l / 3, r = l - p * 3;
        const float c0 = aptd[p * 3 + 0] * inv_l - tr0;
        const float c1 = aptd[p * 3 + 1] * inv_l - tr1;
        const float c2 = aptd[p * 3 + 2] * inv_l - tr2;
        const float* Rm = rot + (size_t)bi * 9 + r * 3;       // R[r][c]
        fb[128 + h * 24 + p * 3 + r] = fmaf(c0, Rm[0], fmaf(c1, Rm[1], c2 * Rm[2]));
    }
    if (l < 8) {
        const float c0 = aptd[l * 3 + 0] * inv_l - tr0;
        const float c1 = aptd[l * 3 + 1] * inv_l - tr1;
        const float c2 = aptd[l * 3 + 2] * inv_l - tr2;
        fb[320 + h * 8 + l] = sqrtf(fmaf(c0, c0, fmaf(c1, c1, fmaf(c2, c2, EPSV))));
    }
}

// ---------------- output projection ----------------
__global__ __launch_bounds__(256) void k_out(
    const float* __restrict__ feats, const float* __restrict__ Wout,
    const float* __restrict__ bout, float* __restrict__ out)
{
    __shared__ float fl[8][896];
    const int t = threadIdx.x;
    const int tok0 = blockIdx.x * 8;
    {
        const float4* src = (const float4*)(feats + (size_t)tok0 * 896);
        float4* dst = (float4*)&fl[0][0];
#pragma unroll
        for (int k = 0; k < 7; ++k) dst[t + 256 * k] = src[t + 256 * k];
    }
    __syncthreads();
    const int tok = t >> 5, l = t & 31;
    float4 acc[3];
#pragma unroll
    for (int m = 0; m < 3; ++m) acc[m] = make_float4(0.f, 0.f, 0.f, 0.f);
    for (int dd = 0; dd < 896; ++dd) {
        float fv = fl[tok][dd];
        const float* wr = Wout + (size_t)dd * 384;
#pragma unroll
        for (int m = 0; m < 3; ++m) {
            float4 wv = *(const float4*)(wr + 4 * (l + 32 * m));
            acc[m].x = fmaf(fv, wv.x, acc[m].x);
            acc[m].y = fmaf(fv, wv.y, acc[m].y);
            acc[m].z = fmaf(fv, wv.z, acc[m].z);
            acc[m].w = fmaf(fv, wv.w, acc[m].w);
        }
    }
    float* ob = out + (size_t)(tok0 + tok) * 384;
#pragma unroll
    for (int m = 0; m < 3; ++m) {
        int c = 4 * (l + 32 * m);
        float4 bv = *(const float4*)(bout + c);
        float4 r = make_float4(acc[m].x + bv.x, acc[m].y + bv.y, acc[m].z + bv.z, acc[m].w + bv.w);
        *(float4*)(ob + c) = r;
    }
}

extern "C" void kernel_launch(void* const* d_in, const int* in_sizes, int n_in,
                              void* d_out, int out_size, void* d_ws, size_t ws_size,
                              hipStream_t stream) {
    const float* x        = (const float*)d_in[0];
    const float* pairw    = (const float*)d_in[1];
    const float* rot      = (const float*)d_in[2];
    const float* trans    = (const float*)d_in[3];
    const int*   pos      = (const int*)d_in[4];
    const float* Wq_s     = (const float*)d_in[6];
    const float* Wk_s     = (const float*)d_in[7];
    const float* Wv_s     = (const float*)d_in[8];
    const float* Wq_p     = (const float*)d_in[9];
    const float* Wk_p     = (const float*)d_in[10];
    const float* Wv_p     = (const float*)d_in[11];
    const float* pweights = (const float*)d_in[12];
    const float* Wpair    = (const float*)d_in[13];
    const float* bpair    = (const float*)d_in[14];
    const float* Wout     = (const float*)d_in[15];
    const float* bout     = (const float*)d_in[16];
    float* out = (float*)d_out;

    float* ws = (float*)d_ws;
    float* cos_t = ws;  ws += 4096;
    float* sin_t = ws;  ws += 4096;
    float* qsg = ws;    ws += BB * HH * NN * DKK;
    float* ksg = ws;    ws += BB * HH * NN * DKK;
    float* vsg = ws;    ws += BB * HH * NN * DVV;
    float* qpg = ws;    ws += BB * HH * NN * 12;
    float* kpg = ws;    ws += BB * HH * NN * 12;
    float* vpg = ws;    ws += BB * HH * NN * 24;
    float* qqg = ws;    ws += BB * HH * NN;
    float* kkg = ws;    ws += BB * HH * NN;
    float* feats = ws;  ws += BB * NN * 896;

    k_rope<<<2, 256, 0, stream>>>(cos_t, sin_t);
    k_proj<<<(BB * NN) / 8, 256, 0, stream>>>(x, rot, trans, pos,
        Wq_s, Wk_s, Wv_s, Wq_p, Wk_p, Wv_p, cos_t, sin_t,
        qsg, ksg, vsg, qpg, kpg, vpg, qqg, kkg);
    k_attn<<<BB * NN, 256, 0, stream>>>(pairw, rot, trans, Wpair, bpair, pweights,
        qsg, ksg, vsg, qpg, kpg, vpg, qqg, kkg, feats);
    k_out<<<(BB * NN) / 8, 256, 0, stream>>>(feats, Wout, bout, out);

    (void)in_sizes; (void)n_in; (void)out_size; (void)ws_size;
}